// Round 1
// baseline (397.630 us; speedup 1.0000x reference)
//
#include <hip/hip_runtime.h>
#include <stdint.h>

#define M_DIM 8192
#define N_DIM 8192
#define K_DIM 1024
#define BK    128

typedef int int4v __attribute__((ext_vector_type(4)));

// ---- async global->LDS, 16B per lane ----
__device__ __forceinline__ void gload16(const char* g, char* l) {
    __builtin_amdgcn_global_load_lds(
        (__attribute__((address_space(1))) void*)(void*)const_cast<char*>(g),
        (__attribute__((address_space(3))) void*)l,
        16, 0, 0);
}

__device__ __forceinline__ int sat8(int v) {
    v = v > 127 ? 127 : v;
    v = v < -128 ? -128 : v;
    return v;
}

// ---- fused pack: blocks [0,8192) pack A; blocks [8192,10240) transpose-pack B ----
__global__ __launch_bounds__(256) void pack_ab_kernel(const int* __restrict__ a,
                                                      const int* __restrict__ b,
                                                      int* __restrict__ outA,
                                                      char* __restrict__ outB) {
    __shared__ char tile[64][68];               // used by B-blocks only
    const int t = threadIdx.x;
    if (blockIdx.x < 8192) {
        // pack a: int32 [M][K] -> int8 [M][K], 4 elems/thread, coalesced
        int i = blockIdx.x * 256 + t;
        int4 v = ((const int4*)a)[i];
        outA[i] = (v.x & 0xff) | ((v.y & 0xff) << 8) |
                  ((v.z & 0xff) << 16) | ((v.w & 0xff) << 24);
        return;
    }
    // pack b: int32 [K][N] -> int8 [N][K] (transpose via LDS tile)
    const int bx = blockIdx.x - 8192;           // 0..2047
    const int n0 = (bx & 127) * 64;
    const int k0 = (bx >> 7) * 64;
    const int tr  = t >> 4;                     // 0..15
    const int tc4 = (t & 15) << 2;              // 0,4,..,60
#pragma unroll
    for (int j = 0; j < 4; ++j) {
        int row = tr + j * 16;                  // k within tile
        int4 v = *(const int4*)&b[(size_t)(k0 + row) * N_DIM + n0 + tc4];
        tile[row][tc4 + 0] = (char)v.x;
        tile[row][tc4 + 1] = (char)v.y;
        tile[row][tc4 + 2] = (char)v.z;
        tile[row][tc4 + 3] = (char)v.w;
    }
    __syncthreads();
#pragma unroll
    for (int j = 0; j < 4; ++j) {
        int n = tr + j * 16;                    // n within tile
        int pk = (tile[tc4 + 0][n] & 0xff) |
                 ((tile[tc4 + 1][n] & 0xff) << 8) |
                 ((tile[tc4 + 2][n] & 0xff) << 16) |
                 ((tile[tc4 + 3][n] & 0xff) << 24);
        *(int*)&outB[(size_t)(n0 + n) * K_DIM + k0 + tc4] = pk;
    }
}

// ---- stage one 16KB half-tile (256 rows x 64B) : 2 x global_load_lds / thread ----
// T2 swizzle: 16B-chunk index in the 64B row is XORed with ((row>>1)&3).
// global_load_lds writes LDS linearly (base + lane*16), so the swizzle is applied
// to the GLOBAL source address (rule 21: pre-swizzled source + swizzled read).
__device__ __forceinline__ void stage_half(const char* __restrict__ gbase,
                                           char* lds, int t, int ktile, int kk) {
#pragma unroll
    for (int i = 0; i < 2; ++i) {
        const int s   = t + i * 512;            // chunk slot 0..1023
        const int row = s >> 2;                 // 0..255
        const int cc  = (s & 3) ^ ((row >> 1) & 3);
        gload16(gbase + ((size_t)row << 10) + ((size_t)(ktile & 7) << 7)
                      + (kk << 6) + (cc << 4),
                lds + s * 16);
    }
}

// ---- GEMM: 256x256 tile, BK=128, 8 waves (2Mx4N), 8-phase counted-vmcnt schedule ----
// Per phase: {ds_read frags | stage 1 half-tile | barrier | lgkm(0) | setprio(1)
//             16 x mfma_i32_16x16x64_i8 | setprio(0) | [vmcnt(8)] barrier}.
// vmcnt(8) only at even-phase boundaries: each staged half has >=4 phases in
// flight before its wait; vmcnt never drains to 0 in the main loop (T3+T4).
// Slot lifecycle (verified): a half-slot is re-staged only in the phase after
// its final reader's closing barrier; each vmcnt(8) retires exactly the half
// needed by the following odd phase's ds_reads.
#define PHASE(BUF, KK, MIH, LOADB, VMW, STG) do {                                   \
    int4v af0 = *(const int4v*)&As[BUF][KK][aRow + ((MIH)*4+0)*16][laneByte];       \
    int4v af1 = *(const int4v*)&As[BUF][KK][aRow + ((MIH)*4+1)*16][laneByte];       \
    int4v af2 = *(const int4v*)&As[BUF][KK][aRow + ((MIH)*4+2)*16][laneByte];       \
    int4v af3 = *(const int4v*)&As[BUF][KK][aRow + ((MIH)*4+3)*16][laneByte];       \
    if (LOADB) {                                                                    \
        bf[0] = *(const int4v*)&Bs[BUF][KK][bRow + 0*16][laneByte];                 \
        bf[1] = *(const int4v*)&Bs[BUF][KK][bRow + 1*16][laneByte];                 \
        bf[2] = *(const int4v*)&Bs[BUF][KK][bRow + 2*16][laneByte];                 \
        bf[3] = *(const int4v*)&Bs[BUF][KK][bRow + 3*16][laneByte];                 \
    }                                                                               \
    STG;                                                                            \
    __builtin_amdgcn_s_barrier();                                                   \
    asm volatile("s_waitcnt lgkmcnt(0)" ::: "memory");                              \
    __builtin_amdgcn_sched_barrier(0);  /* rule 18: MFMA must not hoist past */     \
    __builtin_amdgcn_s_setprio(1);                                                  \
    _Pragma("unroll")                                                               \
    for (int ni = 0; ni < 4; ++ni) {                                                \
        acc[(MIH)*4+0][ni] = __builtin_amdgcn_mfma_i32_16x16x64_i8(af0, bf[ni], acc[(MIH)*4+0][ni], 0,0,0); \
        acc[(MIH)*4+1][ni] = __builtin_amdgcn_mfma_i32_16x16x64_i8(af1, bf[ni], acc[(MIH)*4+1][ni], 0,0,0); \
        acc[(MIH)*4+2][ni] = __builtin_amdgcn_mfma_i32_16x16x64_i8(af2, bf[ni], acc[(MIH)*4+2][ni], 0,0,0); \
        acc[(MIH)*4+3][ni] = __builtin_amdgcn_mfma_i32_16x16x64_i8(af3, bf[ni], acc[(MIH)*4+3][ni], 0,0,0); \
    }                                                                               \
    __builtin_amdgcn_s_setprio(0);                                                  \
    if (VMW) asm volatile("s_waitcnt vmcnt(8)" ::: "memory");                       \
    __builtin_amdgcn_s_barrier();                                                   \
} while (0)

__global__ __launch_bounds__(512, 2) void gemm_i8_kernel(const char* __restrict__ A8,
                                                         const char* __restrict__ B8,
                                                         int* __restrict__ C) {
    // [buf][kk-half][row][64B] : 4 x 16KB half-slots per operand, 128 KiB total
    __shared__ __align__(16) char As[2][2][256][64];
    __shared__ __align__(16) char Bs[2][2][256][64];

    const int t    = threadIdx.x;
    const int bn   = blockIdx.x;
    const int bm   = blockIdx.y;
    const int lane = t & 63;
    const int wave = t >> 6;
    const int wm   = wave >> 2;                  // 0..1 : 128 rows each
    const int wn   = wave & 3;                   // 0..3 : 64 cols each
    const int quad = lane >> 4;
    const int l16  = lane & 15;
    // swizzled 16B-chunk byte offset; ((row>>1)&3) == ((l16>>1)&3) for all frags
    const int laneByte = ((quad ^ ((l16 >> 1) & 3)) << 4);
    const int aRow = wm * 128 + l16;
    const int bRow = wn * 64 + l16;

    const char* aG = A8 + (size_t)(bm * 256) * K_DIM;
    const char* bG = B8 + (size_t)(bn * 256) * K_DIM;

    int4v acc[8][4] = {};
    int4v bf[4];

    // prologue: tile0 {k0,k1} + tile1 {k0} = 12 loads; drain oldest 4 (tile0-k0)
    stage_half(aG, &As[0][0][0][0], t, 0, 0);
    stage_half(bG, &Bs[0][0][0][0], t, 0, 0);
    stage_half(aG, &As[0][1][0][0], t, 0, 1);
    stage_half(bG, &Bs[0][1][0][0], t, 0, 1);
    stage_half(aG, &As[1][0][0][0], t, 1, 0);
    stage_half(bG, &Bs[1][0][0][0], t, 1, 0);
    asm volatile("s_waitcnt vmcnt(8)" ::: "memory");
    __builtin_amdgcn_s_barrier();

    // tiles (2j, 2j+1) computed from bufs (0,1); stage tiles 2j+1..2j+3.
    // Last iteration's stages wrap (ktile&7) -> re-reads hot tiles, slots unused.
#pragma unroll 1
    for (int j = 0; j < K_DIM / BK / 2; ++j) {
        PHASE(0,0,0, 1, 0, stage_half(aG, &As[1][1][0][0], t, 2*j+1, 1));
        PHASE(0,0,1, 0, 1, stage_half(bG, &Bs[1][1][0][0], t, 2*j+1, 1));
        PHASE(0,1,0, 1, 0, stage_half(aG, &As[0][0][0][0], t, 2*j+2, 0));
        PHASE(0,1,1, 0, 1, stage_half(bG, &Bs[0][0][0][0], t, 2*j+2, 0));
        PHASE(1,0,0, 1, 0, stage_half(aG, &As[0][1][0][0], t, 2*j+2, 1));
        PHASE(1,0,1, 0, 1, stage_half(bG, &Bs[0][1][0][0], t, 2*j+2, 1));
        PHASE(1,1,0, 1, 0, stage_half(aG, &As[1][0][0][0], t, 2*j+3, 0));
        PHASE(1,1,1, 0, 1, stage_half(bG, &Bs[1][0][0][0], t, 2*j+3, 0));
    }

    // epilogue: C/D layout col=lane&15, row=4*quad+reg; saturate, store int32
    const int mBase = bm * 256 + wm * 128;
    const int nBase = bn * 256 + wn * 64;
#pragma unroll
    for (int mi = 0; mi < 8; ++mi) {
#pragma unroll
        for (int ni = 0; ni < 4; ++ni) {
            const int col = nBase + ni * 16 + l16;
#pragma unroll
            for (int r = 0; r < 4; ++r) {
                const int row = mBase + mi * 16 + quad * 4 + r;
                C[(size_t)row * N_DIM + col] = sat8(acc[mi][ni][r]);
            }
        }
    }
}

// ---- fallback (only if ws_size < 16MB): direct int32 GEMM, slow but correct ----
__global__ __launch_bounds__(256) void gemm_naive_kernel(const int* __restrict__ a,
                                                         const int* __restrict__ b,
                                                         int* __restrict__ C) {
    const int col = blockIdx.x * 256 + threadIdx.x;
    const int row = blockIdx.y;
    int acc = 0;
    for (int k = 0; k < K_DIM; ++k)
        acc += a[(size_t)row * K_DIM + k] * b[(size_t)k * N_DIM + col];
    C[(size_t)row * N_DIM + col] = sat8(acc);
}

extern "C" void kernel_launch(void* const* d_in, const int* in_sizes, int n_in,
                              void* d_out, int out_size, void* d_ws, size_t ws_size,
                              hipStream_t stream) {
    const int* a = (const int*)d_in[0];
    const int* b = (const int*)d_in[1];
    // alpha_row (d_in[2]) / alpha_col (d_in[3]) are unused in this variant.
    int* out = (int*)d_out;

    const size_t needed = 2 * (size_t)M_DIM * K_DIM;   // 16 MB packed operands
    if (ws_size < needed) {
        gemm_naive_kernel<<<dim3(N_DIM / 256, M_DIM), 256, 0, stream>>>(a, b, out);
        return;
    }

    char* A8 = (char*)d_ws;                          // 8 MB
    char* B8 = A8 + (size_t)M_DIM * K_DIM;           // 8 MB

    pack_ab_kernel<<<8192 + 2048, 256, 0, stream>>>(a, b, (int*)A8, B8);
    gemm_i8_kernel<<<dim3(N_DIM / 256, M_DIM / 256), 512, 0, stream>>>(A8, B8, out);
}

// Round 2
// 363.303 us; speedup vs baseline: 1.0945x; 1.0945x over previous
//
#include <hip/hip_runtime.h>
#include <stdint.h>

#define M_DIM 8192
#define N_DIM 8192
#define K_DIM 1024
#define BK    128

typedef int int4v __attribute__((ext_vector_type(4)));

// ---- async global->LDS, 16B per lane ----
__device__ __forceinline__ void gload16(const char* g, char* l) {
    __builtin_amdgcn_global_load_lds(
        (__attribute__((address_space(1))) void*)(void*)const_cast<char*>(g),
        (__attribute__((address_space(3))) void*)l,
        16, 0, 0);
}

__device__ __forceinline__ int sat8(int v) {
    v = v > 127 ? 127 : v;
    v = v < -128 ? -128 : v;
    return v;
}

// ---- fused pack: blocks [0,8192) pack A; blocks [8192,10240) transpose-pack B ----
__global__ __launch_bounds__(256) void pack_ab_kernel(const int* __restrict__ a,
                                                      const int* __restrict__ b,
                                                      int* __restrict__ outA,
                                                      char* __restrict__ outB) {
    __shared__ char tile[64][68];               // used by B-blocks only
    const int t = threadIdx.x;
    if (blockIdx.x < 8192) {
        // pack a: int32 [M][K] -> int8 [M][K], 4 elems/thread, coalesced
        int i = blockIdx.x * 256 + t;
        int4 v = ((const int4*)a)[i];
        outA[i] = (v.x & 0xff) | ((v.y & 0xff) << 8) |
                  ((v.z & 0xff) << 16) | ((v.w & 0xff) << 24);
        return;
    }
    // pack b: int32 [K][N] -> int8 [N][K] (transpose via LDS tile)
    const int bx = blockIdx.x - 8192;           // 0..2047
    const int n0 = (bx & 127) * 64;
    const int k0 = (bx >> 7) * 64;
    const int tr  = t >> 4;                     // 0..15
    const int tc4 = (t & 15) << 2;              // 0,4,..,60
#pragma unroll
    for (int j = 0; j < 4; ++j) {
        int row = tr + j * 16;                  // k within tile
        int4 v = *(const int4*)&b[(size_t)(k0 + row) * N_DIM + n0 + tc4];
        tile[row][tc4 + 0] = (char)v.x;
        tile[row][tc4 + 1] = (char)v.y;
        tile[row][tc4 + 2] = (char)v.z;
        tile[row][tc4 + 3] = (char)v.w;
    }
    __syncthreads();
#pragma unroll
    for (int j = 0; j < 4; ++j) {
        int n = tr + j * 16;                    // n within tile
        int pk = (tile[tc4 + 0][n] & 0xff) |
                 ((tile[tc4 + 1][n] & 0xff) << 8) |
                 ((tile[tc4 + 2][n] & 0xff) << 16) |
                 ((tile[tc4 + 3][n] & 0xff) << 24);
        *(int*)&outB[(size_t)(n0 + n) * K_DIM + k0 + tc4] = pk;
    }
}

// ---- GEMM: 128x128 tile, BK=128, 4 waves, i8 MFMA (R0 core + T2 swizzle) ----
// R6 lesson (prev session): XCD swizzle regressed — keep natural bn-fast order.
// T2 (this round): R0's frag read As[row*64 + quad*16] with row=...+l16 puts all
// 8 even-l16 lanes of a quad on banks {4q..4q+3} -> 8-way conflict (~2.94x,
// m136) on every ds_read_b128; K-loop was LDS-conflict-bound (~3.4x MFMA time).
// Fix per rule 21 (both-sides-or-neither, LDS dest of global_load_lds must stay
// linear): XOR the 16B-chunk index with (row>>1)&3 on the GLOBAL source address
// at stage time, and read chunk quad^((l16>>1)&3). Both are per-thread consts.
// All frag-row offsets (wm*64, mi*16) are multiples of 16, so
// (row>>1)&3 == (l16>>1)&3 for every fragment -> read data chunk == quad.
__global__ __launch_bounds__(256) void gemm_i8_kernel(const char* __restrict__ A8,
                                                      const char* __restrict__ B8,
                                                      int* __restrict__ C) {
    __shared__ __align__(16) char As[2 * 128 * 64];   // [k64-half][m][64B]
    __shared__ __align__(16) char Bs[2 * 128 * 64];   // [k64-half][n][64B]

    const int t    = threadIdx.x;
    const int bn   = blockIdx.x;
    const int bm   = blockIdx.y;
    const int lane = t & 63;
    const int wave = t >> 6;
    const int wm   = wave >> 1;                  // 2x2 wave grid, 64x64 per wave
    const int wn   = wave & 1;
    const int quad = lane >> 4;
    const int l16  = lane & 15;

    const size_t aBase = (size_t)(bm * 128) * K_DIM;
    const size_t bBase = (size_t)(bn * 128) * K_DIM;

    // staging: 4 slots/operand/thread, 16 B each
    const int sr = t >> 2;                       // row within 64-row half
    // swizzled source chunk: slot (t&3) fetches global chunk (t&3)^((row>>1)&3),
    // row = (t>>2) within the 64-row half (the s-bit adds row-bit6: >>1 -> bit5,
    // &3 == 0, so it drops out) -> per-thread constant.
    const int swzc = (((t & 3) ^ ((t >> 3) & 3)) << 4);
    // swizzled read chunk byte offset (per-lane constant, see header comment)
    const int laneByte = ((quad ^ ((l16 >> 1) & 3)) << 4);

    int4v acc[4][4] = {};

    for (int kt = 0; kt < K_DIM / BK; ++kt) {
        const int kOff = kt * BK;
#pragma unroll
        for (int s = 0; s < 4; ++s) {
            const int p = s >> 1;                // K64-half
            const int rr = ((s & 1) << 6) + sr;  // tile row
            const int f = s * 4096 + t * 16;     // LDS flat offset (linear dest)
            gload16(A8 + aBase + (size_t)rr * K_DIM + kOff + p * 64 + swzc, As + f);
            gload16(B8 + bBase + (size_t)rr * K_DIM + kOff + p * 64 + swzc, Bs + f);
        }
        __syncthreads();   // drains vmcnt -> staged data visible

#pragma unroll
        for (int h = 0; h < 2; ++h) {            // two K64-halves per stage
            int4v af[4], bf[4];
#pragma unroll
            for (int mi = 0; mi < 4; ++mi)
                af[mi] = *(const int4v*)
                    &As[h * 8192 + (wm * 64 + mi * 16 + l16) * 64 + laneByte];
#pragma unroll
            for (int ni = 0; ni < 4; ++ni)
                bf[ni] = *(const int4v*)
                    &Bs[h * 8192 + (wn * 64 + ni * 16 + l16) * 64 + laneByte];

#pragma unroll
            for (int mi = 0; mi < 4; ++mi)
#pragma unroll
                for (int ni = 0; ni < 4; ++ni)
                    acc[mi][ni] = __builtin_amdgcn_mfma_i32_16x16x64_i8(
                        af[mi], bf[ni], acc[mi][ni], 0, 0, 0);
        }

        __syncthreads();   // LDS reads done before next stage overwrites
    }

    // epilogue: C/D layout col=lane&15, row=4*quad+reg; saturate, store int32
    const int mBase = bm * 128 + wm * 64;
    const int nBase = bn * 128 + wn * 64;
#pragma unroll
    for (int mi = 0; mi < 4; ++mi) {
#pragma unroll
        for (int ni = 0; ni < 4; ++ni) {
            const int col = nBase + ni * 16 + l16;
#pragma unroll
            for (int r = 0; r < 4; ++r) {
                const int row = mBase + mi * 16 + quad * 4 + r;
                C[(size_t)row * N_DIM + col] = sat8(acc[mi][ni][r]);
            }
        }
    }
}

// ---- fallback (only if ws_size < 16MB): direct int32 GEMM, slow but correct ----
__global__ __launch_bounds__(256) void gemm_naive_kernel(const int* __restrict__ a,
                                                         const int* __restrict__ b,
                                                         int* __restrict__ C) {
    const int col = blockIdx.x * 256 + threadIdx.x;
    const int row = blockIdx.y;
    int acc = 0;
    for (int k = 0; k < K_DIM; ++k)
        acc += a[(size_t)row * K_DIM + k] * b[(size_t)k * N_DIM + col];
    C[(size_t)row * N_DIM + col] = sat8(acc);
}

extern "C" void kernel_launch(void* const* d_in, const int* in_sizes, int n_in,
                              void* d_out, int out_size, void* d_ws, size_t ws_size,
                              hipStream_t stream) {
    const int* a = (const int*)d_in[0];
    const int* b = (const int*)d_in[1];
    // alpha_row (d_in[2]) / alpha_col (d_in[3]) are unused in this variant.
    int* out = (int*)d_out;

    const size_t needed = 2 * (size_t)M_DIM * K_DIM;   // 16 MB packed operands
    if (ws_size < needed) {
        gemm_naive_kernel<<<dim3(N_DIM / 256, M_DIM), 256, 0, stream>>>(a, b, out);
        return;
    }

    char* A8 = (char*)d_ws;                          // 8 MB
    char* B8 = A8 + (size_t)M_DIM * K_DIM;           // 8 MB

    pack_ab_kernel<<<8192 + 2048, 256, 0, stream>>>(a, b, (int*)A8, B8);
    gemm_i8_kernel<<<dim3(N_DIM / 128, M_DIM / 128), 256, 0, stream>>>(A8, B8, out);
}